// Round 6
// baseline (344.645 us; speedup 1.0000x reference)
//
#include <hip/hip_runtime.h>

// B = 1048576 rows, D = 64. xc = [x, sin(x)] (width 128).
// out[row] = { xc . w_sum + b,  exp2( log2|xc| . w_prod ) }
//
// 8 lanes per row; lane q = tid&7 owns x-cols [4q..4q+3] and [32+4q..32+4q+3].
// R6: software-pipelined ring buffer (depth PF=4) instead of a 16-load burst:
//  - only 32 data VGPRs live -> higher occupancy (vs 4 waves/SIMD in R5)
//  - each wave issues fresh loads DURING compute -> continuous memory issue,
//    no burst-then-drain phase alignment across block generations
//  - ITER=16 halves the number of block generations (2048 blocks)

typedef float vf4 __attribute__((ext_vector_type(4)));
typedef float vf2 __attribute__((ext_vector_type(2)));

#define BLOCK 256
#define ITER 16
#define PF 4
#define INV_2PI 0.15915494309189535f

__global__ __launch_bounds__(BLOCK) void fb_kernel(
    const vf4* __restrict__ x4,
    const vf4* __restrict__ wsum4,
    const float* __restrict__ b_sum,
    const vf4* __restrict__ wprod4,
    vf2*       __restrict__ out)
{
    const int tid = threadIdx.x;
    const int q   = tid & 7;

    // w[0..15] = x-part (cols 0..63), w[16..31] = sin-part, float4 units
    const vf4 wsA = wsum4[q];
    const vf4 wsB = wsum4[8 + q];
    const vf4 wsC = wsum4[16 + q];
    const vf4 wsD = wsum4[24 + q];
    const vf4 wpA = wprod4[q];
    const vf4 wpB = wprod4[8 + q];
    const vf4 wpC = wprod4[16 + q];
    const vf4 wpD = wprod4[24 + q];
    const float bias = b_sum[0];

    const int stride = gridDim.x * BLOCK;      // slice units (8 per row)
    const int g0     = blockIdx.x * BLOCK + tid;

    vf4 va[PF], vb[PF];
    int row[PF];

    // ---- prologue: fill the ring ----
#pragma unroll
    for (int i = 0; i < PF; ++i) {
        const int g    = g0 + i * stride;
        row[i]         = g >> 3;               // g ≡ tid (mod 8)
        const int base = row[i] * 16 + q;
        va[i] = __builtin_nontemporal_load(&x4[base]);
        vb[i] = __builtin_nontemporal_load(&x4[base + 8]);
    }

    // ---- steady state: compute slot, refill slot ----
#pragma unroll
    for (int it = 0; it < ITER; ++it) {
        const int sl = it % PF;                // constant after unroll
        const vf4 A = va[sl];
        const vf4 Bv = vb[sl];
        const int r  = row[sl];

        if (it + PF < ITER) {
            const int g    = g0 + (it + PF) * stride;
            row[sl]        = g >> 3;
            const int base = row[sl] * 16 + q;
            va[sl] = __builtin_nontemporal_load(&x4[base]);
            vb[sl] = __builtin_nontemporal_load(&x4[base + 8]);
        }

        float s = 0.f;   // sum-head partial
        float p = 0.f;   // product-head partial (base-2 log domain)

#define ELEM(X, WS, WSS, WP, WPS)                            \
        {                                                    \
            const float xx = (X);                            \
            const float sx = __builtin_amdgcn_sinf(xx * INV_2PI); \
            s = fmaf(xx, (WS),  s);                          \
            s = fmaf(sx, (WSS), s);                          \
            p = fmaf(__log2f(fabsf(xx)), (WP),  p);          \
            p = fmaf(__log2f(fabsf(sx)), (WPS), p);          \
        }

        ELEM(A.x,  wsA.x, wsC.x, wpA.x, wpC.x)
        ELEM(A.y,  wsA.y, wsC.y, wpA.y, wpC.y)
        ELEM(A.z,  wsA.z, wsC.z, wpA.z, wpC.z)
        ELEM(A.w,  wsA.w, wsC.w, wpA.w, wpC.w)
        ELEM(Bv.x, wsB.x, wsD.x, wpB.x, wpD.x)
        ELEM(Bv.y, wsB.y, wsD.y, wpB.y, wpD.y)
        ELEM(Bv.z, wsB.z, wsD.z, wpB.z, wpD.z)
        ELEM(Bv.w, wsB.w, wsD.w, wpB.w, wpD.w)
#undef ELEM

#pragma unroll
        for (int off = 4; off > 0; off >>= 1) {
            s += __shfl_xor(s, off);
            p += __shfl_xor(p, off);
        }

        if (q == 0) {
            // exp(sum ln) == exp2(sum log2); v_exp_f32 is native exp2
            vf2 rres;
            rres.x = s + bias;
            rres.y = __builtin_amdgcn_exp2f(p);
            __builtin_nontemporal_store(rres, &out[r]);
        }
    }
}

extern "C" void kernel_launch(void* const* d_in, const int* in_sizes, int n_in,
                              void* d_out, int out_size, void* d_ws, size_t ws_size,
                              hipStream_t stream)
{
    const vf4*  x4     = (const vf4*)d_in[0];
    const vf4*  wsum4  = (const vf4*)d_in[1];
    const float* b_sum = (const float*)d_in[2];
    const vf4*  wprod4 = (const vf4*)d_in[3];
    vf2*        out    = (vf2*)d_out;

    const long rows   = (long)in_sizes[0] / 64;            // 1,048,576
    const int  blocks = (int)(rows * 8 / (BLOCK * ITER));  // 2048 (exact)

    hipLaunchKernelGGL(fb_kernel, dim3(blocks), dim3(BLOCK), 0, stream,
                       x4, wsum4, b_sum, wprod4, out);
}

// Round 7
// 338.855 us; speedup vs baseline: 1.0171x; 1.0171x over previous
//
#include <hip/hip_runtime.h>

// B = 1048576 rows, D = 64. xc = [x, sin(x)] (width 128).
// out[row] = { xc . w_sum + b,  exp2( log2|xc| . w_prod ) }
//
// Best structure (R5): 8 lanes/row, lane q = tid&7 owns x-cols [4q..4q+3] and
// [32+4q..32+4q+3]; ITER=8 rows grid-strided; all 16 nontemporal dwordx4
// loads issued up front; __launch_bounds__(256,4).
//
// R7 tweak: split-role butterfly reduction — stage 0 (xor 4) exchanges BOTH
// s and p, then lanes 0-3 carry the S-partials and lanes 4-7 the P-partials
// through xor-2 / xor-1: 4 ds ops per row-group instead of 6. Lane 0 stores
// out[r].x, lane 4 stores out[r].y (two dword stores, 8 MiB total).

typedef float vf4 __attribute__((ext_vector_type(4)));

#define BLOCK 256
#define ITER 8
#define INV_2PI 0.15915494309189535f

__global__ __launch_bounds__(BLOCK, 4) void fb_kernel(
    const vf4* __restrict__ x4,
    const vf4* __restrict__ wsum4,
    const float* __restrict__ b_sum,
    const vf4* __restrict__ wprod4,
    float*     __restrict__ out)   // out[row*2] = sum head, out[row*2+1] = prod head
{
    const int tid = threadIdx.x;
    const int q   = tid & 7;

    // w[0..15] = x-part (cols 0..63), w[16..31] = sin-part, float4 units
    const vf4 wsA = wsum4[q];
    const vf4 wsB = wsum4[8 + q];
    const vf4 wsC = wsum4[16 + q];
    const vf4 wsD = wsum4[24 + q];
    const vf4 wpA = wprod4[q];
    const vf4 wpB = wprod4[8 + q];
    const vf4 wpC = wprod4[16 + q];
    const vf4 wpD = wprod4[24 + q];
    const float bias = b_sum[0];

    const int stride = gridDim.x * BLOCK;      // slice units (8 per row)
    const int g0     = blockIdx.x * BLOCK + tid;

    // ---- issue all loads first (nontemporal: pure streaming, no reuse) ----
    vf4 va[ITER], vb[ITER];
    int row[ITER];
#pragma unroll
    for (int it = 0; it < ITER; ++it) {
        const int g    = g0 + it * stride;
        row[it]        = g >> 3;               // g ≡ tid (mod 8)
        const int base = row[it] * 16 + q;
        va[it] = __builtin_nontemporal_load(&x4[base]);
        vb[it] = __builtin_nontemporal_load(&x4[base + 8]);
    }

    // ---- compute + reduce + store per row ----
#pragma unroll
    for (int it = 0; it < ITER; ++it) {
        float s = 0.f;   // sum-head partial
        float p = 0.f;   // product-head partial (base-2 log domain)

#define ELEM(X, WS, WSS, WP, WPS)                            \
        {                                                    \
            const float xx = (X);                            \
            const float sx = __builtin_amdgcn_sinf(xx * INV_2PI); \
            s = fmaf(xx, (WS),  s);                          \
            s = fmaf(sx, (WSS), s);                          \
            p = fmaf(__log2f(fabsf(xx)), (WP),  p);          \
            p = fmaf(__log2f(fabsf(sx)), (WPS), p);          \
        }

        ELEM(va[it].x, wsA.x, wsC.x, wpA.x, wpC.x)
        ELEM(va[it].y, wsA.y, wsC.y, wpA.y, wpC.y)
        ELEM(va[it].z, wsA.z, wsC.z, wpA.z, wpC.z)
        ELEM(va[it].w, wsA.w, wsC.w, wpA.w, wpC.w)
        ELEM(vb[it].x, wsB.x, wsD.x, wpB.x, wpD.x)
        ELEM(vb[it].y, wsB.y, wsD.y, wpB.y, wpD.y)
        ELEM(vb[it].z, wsB.z, wsD.z, wpB.z, wpD.z)
        ELEM(vb[it].w, wsB.w, wsD.w, wpB.w, wpD.w)
#undef ELEM

        // split-role butterfly: stage 0 pairs lanes q and q^4 for both values,
        // then lanes 0-3 reduce S while lanes 4-7 reduce P.
        const float s2 = s + __shfl_xor(s, 4);
        const float p2 = p + __shfl_xor(p, 4);
        float z = (q & 4) ? p2 : s2;
        z += __shfl_xor(z, 2);
        z += __shfl_xor(z, 1);
        // lanes 0-3 hold S; lanes 4-7 hold P

        if (q == 0) {
            out[row[it] * 2] = z + bias;
        } else if (q == 4) {
            // exp(sum ln) == exp2(sum log2); v_exp_f32 is native exp2
            out[row[it] * 2 + 1] = __builtin_amdgcn_exp2f(z);
        }
    }
}

extern "C" void kernel_launch(void* const* d_in, const int* in_sizes, int n_in,
                              void* d_out, int out_size, void* d_ws, size_t ws_size,
                              hipStream_t stream)
{
    const vf4*  x4     = (const vf4*)d_in[0];
    const vf4*  wsum4  = (const vf4*)d_in[1];
    const float* b_sum = (const float*)d_in[2];
    const vf4*  wprod4 = (const vf4*)d_in[3];
    float*      out    = (float*)d_out;

    const long rows   = (long)in_sizes[0] / 64;            // 1,048,576
    const int  blocks = (int)(rows * 8 / (BLOCK * ITER));  // 4096 (exact)

    hipLaunchKernelGGL(fb_kernel, dim3(blocks), dim3(BLOCK), 0, stream,
                       x4, wsum4, b_sum, wprod4, out);
}